// Round 1
// 271.430 us; speedup vs baseline: 1.0794x; 1.0794x over previous
//
#include <hip/hip_runtime.h>

#define N_BATCH 256
#define SEQ     2048
#define L       50
#define CORE    58                  // output rows per block
#define HALO    3                   // iteration dependency radius
#define SP      72                  // p_s row stride in bf16 (144 B, 16B-aligned)
#define SB      72                  // B row stride in bf16
#define ITER    3

#define L2E 1.4426950408889634f
#define LN2 0.6931471805599453f

typedef __attribute__((ext_vector_type(8))) short bf16x8;
typedef __attribute__((ext_vector_type(4))) float f32x4;

__device__ __forceinline__ unsigned short f2b(float f) {
    unsigned int u = __builtin_bit_cast(unsigned int, f);
    u += 0x7FFFu + ((u >> 16) & 1u);            // RTNE
    return (unsigned short)(u >> 16);
}

// gfx950 packed f32->bf16 (RTNE), replaces 2x f2b (8 VALU ops) with 1 inst
__device__ __forceinline__ unsigned int cvt_pk_bf16(float lo, float hi) {
    unsigned int r;
    asm("v_cvt_pk_bf16_f32 %0, %1, %2" : "=v"(r) : "v"(lo), "v"(hi));
    return r;
}

template <int CTRL>
__device__ __forceinline__ float dpp_mov_f32(float x) {
    int xi = __builtin_bit_cast(int, x);
    int r  = __builtin_amdgcn_update_dpp(xi, xi, CTRL, 0xF, 0xF, false);
    return __builtin_bit_cast(float, r);
}

// sum across the 16-lane group (nloc) entirely on the VALU (no ds_swizzle):
// xor1 = quad_perm(1,0,3,2)=0xB1, xor2 = quad_perm(2,3,0,1)=0x4E,
// then row_ror:4 (0x124) + row_ror:8 (0x128) complete the 16-lane reduction.
__device__ __forceinline__ float rowsum16(float s) {
    s += dpp_mov_f32<0xB1>(s);
    s += dpp_mov_f32<0x4E>(s);
    s += dpp_mov_f32<0x124>(s);
    s += dpp_mov_f32<0x128>(s);
    return s;
}

__device__ __forceinline__ float fexp2(float x) {
#if __has_builtin(__builtin_amdgcn_exp2f)
    return __builtin_amdgcn_exp2f(x);
#else
    return __expf(x * LN2);
#endif
}

// k-dim permutation: k' = (k&15)*4 + (k>>4). Applied to BOTH p_s writes and
// BL/BR staging -> MFMA contraction unchanged (bijection on k), but each
// lane's 4 softmax outputs (cols nloc,16+nloc,32+nloc,48+nloc) land at
// contiguous k' = 4*nloc..4*nloc+3 -> one ds_write_b64, bank-conflict-free.
#define KPERM(k) ((((k) & 15) << 2) | ((k) >> 4))

// waves_per_eu(4,8): allocator budget 128 regs (est. peak ~115 live incl. the
// 64-reg persistent B fragments) -> 4-5 waves/EU vs the old (3,3) 3-wave pin.
__global__ __attribute__((amdgpu_waves_per_eu(4, 8))) __launch_bounds__(256)
void mfvi_kernel(
    const float* __restrict__ unary,
    const float* __restrict__ mask,
    const float* __restrict__ trans,   // [L][L]
    const float* __restrict__ tstart,  // [L]
    const float* __restrict__ tend,    // [L]
    float* __restrict__ out)
{
    // Single LDS pool: B staging (18432 B) lives only until fragment
    // extraction, then p_s (9216 B) overlays it. 18432 B -> 8 blocks/CU LDS cap.
    __shared__ __attribute__((aligned(16))) unsigned short SH[2 * 64 * SB]; // 18432 B
    unsigned short* BLs = SH;               // BL[n][k'] = T[k][n]
    unsigned short* BRs = SH + 64 * SB;     // BR[n][k'] = T[n][k]
    unsigned short* p_s = SH;               // overlays BLs after extraction

    const int tid   = threadIdx.x;
    const int lane  = tid & 63;
    const int wave  = tid >> 6;
    const int nloc  = lane & 15;
    const int quad  = lane >> 4;
    const int nb    = blockIdx.y;
    const int s0    = blockIdx.x * CORE;
    const int tile0 = s0 - HALO + wave * 16;   // global seq row of this wave's tile row 0

    // ---------- early global loads (in flight across LDS setup) ----------
    float uraw[4][4], mk[4], tsv[4], tev[4];
#pragma unroll
    for (int nt = 0; nt < 4; ++nt) {
        int c = nt * 16 + nloc;
        bool cl = c < L;
        tsv[nt] = cl ? tstart[c] : 0.f;
        tev[nt] = cl ? tend[c]   : 0.f;
    }
#pragma unroll
    for (int reg = 0; reg < 4; ++reg) {
        int g = tile0 + quad * 4 + reg;
        bool in = (unsigned)g < (unsigned)SEQ;
        mk[reg] = in ? mask[nb * SEQ + g] : 0.f;
#pragma unroll
        for (int nt = 0; nt < 4; ++nt) {
            int c = nt * 16 + nloc;
            bool cv = in && (c < L);
            uraw[nt][reg] = cv ? unary[((size_t)nb * SEQ + g) * L + c] : 0.f;
        }
    }

    // ---------- zero staging (pad rows/cols of BL/BR must be finite 0) ----------
    {
        uint2 z; z.x = 0u; z.y = 0u;
        uint2* p = (uint2*)SH;
        for (int i = tid; i < (2 * 64 * SB) / 4; i += 256) p[i] = z;
    }
    __syncthreads();

    // ---------- stage T: coalesced read, k-permuted LDS scatter ----------
    for (int i = tid; i < L * L; i += 256) {
        int r = i / L, c = i - r * L;
        unsigned short v = f2b(trans[i]);
        BLs[c * SB + KPERM(r)] = v;
        BRs[r * SB + KPERM(c)] = v;
    }
    __syncthreads();

    // ---------- B fragments -> registers (64 VGPRs, persistent) ----------
    bf16x8 bL[2][4], bR[2][4];
#pragma unroll
    for (int kk = 0; kk < 2; ++kk)
#pragma unroll
        for (int nt = 0; nt < 4; ++nt) {
            int off = (nt * 16 + nloc) * SB + kk * 32 + quad * 8;
            bL[kk][nt] = *(const bf16x8*)&BLs[off];
            bR[kk][nt] = *(const bf16x8*)&BRs[off];
        }
    __syncthreads();   // staging dead; p_s region live from here

    // ---------- q / umm in log2e domain: softmax uses raw v_exp_f32 ----------
    // q' = q*log2e; softmax(q) == 2^q' normalized; final out = q'_final * ln2.
    float q[4][4], umm[4][4];
#pragma unroll
    for (int reg = 0; reg < 4; ++reg) {
        int g = tile0 + quad * 4 + reg;
#pragma unroll
        for (int nt = 0; nt < 4; ++nt) {
            float bnd = (g == 0) ? tsv[nt] : tev[nt];   // already 0 for c>=L / OOR
            float qv  = uraw[nt][reg] * mk[reg];
            q[nt][reg]   = qv * L2E;
            umm[nt][reg] = (qv + bnd) * (mk[reg] * L2E);
        }
        mk[reg] *= L2E;   // epilogue scale: q' = umm' + mk'*acc
    }

    const int myrow = wave * 16 + quad * 4;
    int slL = wave * 16 + nloc - 1; if (slL < 0)  slL = 0;   // clamped -> don't-care rows
    int slR = wave * 16 + nloc + 1; if (slR > 63) slR = 63;
    unsigned short*       pw  = &p_s[myrow * SP + 4 * nloc]; // b64 write base (8B-aligned)
    const unsigned short* paL = &p_s[slL * SP + quad * 8];
    const unsigned short* paR = &p_s[slR * SP + quad * 8];
    const int grow0 = tile0 + quad * 4;

    // ---------- iterations: global-free ----------
    for (int it = 0; it < ITER; ++it) {
        const bool v3 = (nloc < 2);                           // col 48+nloc < 50
#pragma unroll
        for (int reg = 0; reg < 4; ++reg) {
            float e0 = fexp2(q[0][reg]);
            float e1 = fexp2(q[1][reg]);
            float e2 = fexp2(q[2][reg]);
            float e3 = v3 ? fexp2(q[3][reg]) : 0.f;
            float s  = rowsum16(e0 + e1 + e2 + e3);
            int g = grow0 + reg;
            float inv = ((unsigned)g < (unsigned)SEQ) ? __builtin_amdgcn_rcpf(s) : 0.f;
            uint2 pk;
            pk.x = cvt_pk_bf16(e0 * inv, e1 * inv);
            pk.y = cvt_pk_bf16(e2 * inv, e3 * inv);
            *(uint2*)(pw + reg * SP) = pk;                    // ds_write_b64, conflict-free
        }
        __syncthreads();   // p ready

        f32x4 acc[4];
#pragma unroll
        for (int nt = 0; nt < 4; ++nt) {
            acc[nt][0] = 0.f; acc[nt][1] = 0.f; acc[nt][2] = 0.f; acc[nt][3] = 0.f;
        }
#pragma unroll
        for (int kk = 0; kk < 2; ++kk) {
            bf16x8 aL = *(const bf16x8*)(paL + kk * 32);
            bf16x8 aR = *(const bf16x8*)(paR + kk * 32);
#pragma unroll
            for (int nt = 0; nt < 4; ++nt) {
                acc[nt] = __builtin_amdgcn_mfma_f32_16x16x32_bf16(aL, bL[kk][nt], acc[nt], 0, 0, 0);
                acc[nt] = __builtin_amdgcn_mfma_f32_16x16x32_bf16(aR, bR[kk][nt], acc[nt], 0, 0, 0);
            }
        }
        __syncthreads();   // p_s reads done before next iteration's writes

#pragma unroll
        for (int reg = 0; reg < 4; ++reg)
#pragma unroll
            for (int nt = 0; nt < 4; ++nt)
                q[nt][reg] = umm[nt][reg] + mk[reg] * acc[nt][reg];
    }

    // ---------- direct store (64B segments per quad; ln2 undoes log2e domain) ----------
#pragma unroll
    for (int reg = 0; reg < 4; ++reg) {
        int g = tile0 + quad * 4 + reg;
        if (g >= s0 && g < s0 + CORE && g < SEQ) {
            float* orow = out + ((size_t)nb * SEQ + g) * L;
#pragma unroll
            for (int nt = 0; nt < 4; ++nt) {
                int c = nt * 16 + nloc;
                if (c < L) orow[c] = q[nt][reg] * LN2;
            }
        }
    }
}

extern "C" void kernel_launch(void* const* d_in, const int* in_sizes, int n_in,
                              void* d_out, int out_size, void* d_ws, size_t ws_size,
                              hipStream_t stream) {
    const float* unary  = (const float*)d_in[0];
    const float* mask   = (const float*)d_in[1];
    const float* trans  = (const float*)d_in[2];
    const float* tstart = (const float*)d_in[3];
    const float* tend   = (const float*)d_in[4];
    float* out = (float*)d_out;

    dim3 grid((SEQ + CORE - 1) / CORE, N_BATCH);   // 36 x 256
    mfvi_kernel<<<grid, dim3(256), 0, stream>>>(unary, mask, trans, tstart, tend, out);
}